// Round 17
// baseline (249.196 us; speedup 1.0000x reference)
//
#include <hip/hip_runtime.h>

#define NN 50000
#define NE 800000
#define NT (NE + NN)   /* 850000 edges incl self-loops */
#define NG 64
#define NBKT ((NN + 255) / 256)  /* 196 dst buckets of 256 nodes */
#define CAP 5120               /* staging capacity per bucket (mean 4352, +11.7 sigma) */
#define CHA 4096               /* pass-A edges per block */
#define NA ((NT + CHA - 1) / CHA) /* 208 pass-A blocks */

typedef __attribute__((ext_vector_type(8))) short short8;
typedef __attribute__((ext_vector_type(8))) unsigned short ushort8;
typedef __attribute__((ext_vector_type(4))) float f32x4;
typedef __attribute__((ext_vector_type(2))) float f32x2;

__device__ __forceinline__ float leaky(float v) { return fmaxf(v, 0.2f * v); }

__device__ __forceinline__ unsigned short f2bf(float f) {
  unsigned u = __float_as_uint(f);
  unsigned r = (u + 0x7fffu + ((u >> 16) & 1u)) >> 16;
  return (unsigned short)r;
}
__device__ __forceinline__ float bf2f(unsigned short s) {
  return __uint_as_float(((unsigned)s) << 16);
}

// ---------- prep: Wl2||Wr2 -> bf16 (128 blocks) + bcur init (1 block) ----------
__global__ void k_prep(const float* __restrict__ Wl2, const float* __restrict__ Wr2,
                       short* __restrict__ Wb, int* __restrict__ bcur) {
  int b = blockIdx.x;
  if (b < 128) {
    int idx = b * 256 + threadIdx.x;  // 128*256 elems
    int n = idx >> 8, k = idx & 255;
    float v = (n < 64) ? Wl2[n * 256 + k] : Wr2[(n - 64) * 256 + k];
    int nt = n >> 4, ks = k >> 5;
    int l = (n & 15) + (((k >> 3) & 3) << 4);
    int j = k & 7;
    Wb[(((nt * 8 + ks) * 64 + l) << 3) + j] = (short)f2bf(v);
  } else {
    int t = threadIdx.x;
    if (t < NBKT) bcur[t] = t * CAP;
  }
}

// ---------- pass A: bucket the edges into fixed-capacity staging ----------
__global__ __launch_bounds__(256) void k_passA(const int* __restrict__ ei,
                                               int* __restrict__ bcur,
                                               int2* __restrict__ staging) {
  __shared__ int hist[NBKT];
  __shared__ int cur[NBKT];
  int t = threadIdx.x;
  int e0 = blockIdx.x * CHA;
  for (int i = t; i < NBKT; i += 256) hist[i] = 0;
  __syncthreads();
  for (int i = t; i < CHA; i += 256) {
    int e = e0 + i;
    if (e < NT) {
      int dst = (e < NE) ? ei[NE + e] : e - NE;
      atomicAdd(&hist[dst >> 8], 1);
    }
  }
  __syncthreads();
  for (int i = t; i < NBKT; i += 256) {
    int h = hist[i];
    cur[i] = h ? atomicAdd(&bcur[i], h) : 0;
  }
  __syncthreads();
  for (int i = t; i < CHA; i += 256) {
    int e = e0 + i;
    if (e < NT) {
      int src, dst;
      if (e < NE) { src = ei[e]; dst = ei[NE + e]; } else { src = dst = e - NE; }
      int pos = atomicAdd(&cur[dst >> 8], 1);
      staging[pos] = make_int2(src, dst);
    }
  }
}

// ---------- bucket scan: counts (from bcur) -> CSR bases (one block) ----------
__global__ __launch_bounds__(256) void k_bktscan2(const int* __restrict__ bcur,
                                                  int* __restrict__ bktbase) {
  __shared__ int wsum[4];
  int t = threadIdx.x;
  int lane = t & 63, w = t >> 6;
  int v = (t < NBKT) ? (bcur[t] - t * CAP) : 0;
  int incl = v;
#pragma unroll
  for (int off = 1; off < 64; off <<= 1) {
    int u = __shfl_up(incl, off, 64);
    if (lane >= off) incl += u;
  }
  if (lane == 63) wsum[w] = incl;
  __syncthreads();
  int woff = 0;
  for (int i = 0; i < w; i++) woff += wsum[i];
  int excl = woff + incl - v;
  if (t < NBKT) bktbase[t] = excl;
  if (t == 0) bktbase[NBKT] = NT;
}

// ---------- pass B: node hist + scan -> rowptr; scatter csr_src (L2-local) ----------
__global__ __launch_bounds__(256) void k_passB(const int* __restrict__ bktbase,
                                               const int* __restrict__ bcur,
                                               const int2* __restrict__ staging,
                                               int* __restrict__ rowptr,
                                               int* __restrict__ csr_src) {
  __shared__ int cnt[256];
  __shared__ int wsum[4];
  __shared__ int cur[256];
  int b = blockIdx.x, t = threadIdx.x;
  int nb0 = b * 256;
  int s0 = b * CAP;                 // staging base
  int s1v = bcur[b];                // staging end
  int r0 = bktbase[b];              // CSR base
  cnt[t] = 0;
  __syncthreads();
  for (int i = s0 + t; i < s1v; i += 256)
    atomicAdd(&cnt[staging[i].y - nb0], 1);
  __syncthreads();
  int v = cnt[t];
  int lane = t & 63, w = t >> 6;
  int incl = v;
#pragma unroll
  for (int off = 1; off < 64; off <<= 1) {
    int u = __shfl_up(incl, off, 64);
    if (lane >= off) incl += u;
  }
  if (lane == 63) wsum[w] = incl;
  __syncthreads();
  int woff = 0;
  for (int i = 0; i < w; i++) woff += wsum[i];
  int base = r0 + woff + incl - v;   // exclusive within bucket
  if (nb0 + t < NN) rowptr[nb0 + t] = base;
  if (b == NBKT - 1 && t == 0) rowptr[NN] = NT;
  cur[t] = base;
  __syncthreads();
  for (int i = s0 + t; i < s1v; i += 256) {
    int2 e = staging[i];
    int pos = atomicAdd(&cur[e.y - nb0], 1);
    csr_src[pos] = e.x;
  }
}

// ---------- conv1: EXACT R12-measured kernel (76.0us) ----------
__global__ __launch_bounds__(256) void k_conv1(
    const float* __restrict__ x, const int* __restrict__ rowptr,
    const int* __restrict__ csr_src,
    const float* __restrict__ Wl1, const float* __restrict__ bl1,
    const float* __restrict__ Wr1, const float* __restrict__ br1,
    const float* __restrict__ att1, float* __restrict__ s1) {
  int lane = threadIdx.x & 63;
  int node = blockIdx.x * 4 + (threadIdx.x >> 6);
  if (node >= NN) return;
  int sub = lane & 15, grp = lane >> 4;
  const float2* x2 = (const float2*)x;
  float2 xd = x2[node];
  f32x2 A0[4][2], A1[4][2], R[4][2], AT[4][2];
#pragma unroll
  for (int h = 0; h < 4; h++)
#pragma unroll
    for (int p = 0; p < 2; p++) {
      int c0 = h * 64 + sub * 4 + 2 * p;
      A0[h][p] = (f32x2){Wl1[c0 * 2], Wl1[(c0 + 1) * 2]};
      A1[h][p] = (f32x2){Wl1[c0 * 2 + 1], Wl1[(c0 + 1) * 2 + 1]};
      R[h][p]  = (f32x2){Wr1[c0 * 2] * xd.x + Wr1[c0 * 2 + 1] * xd.y + bl1[c0] + br1[c0],
                         Wr1[(c0 + 1) * 2] * xd.x + Wr1[(c0 + 1) * 2 + 1] * xd.y + bl1[c0 + 1] + br1[c0 + 1]};
      AT[h][p] = (f32x2){att1[c0], att1[c0 + 1]};
    }
  float ax = 0.f, ay = 0.f, ad = 0.f;
  int start = rowptr[node], end = rowptr[node + 1];
  for (int cb = start; cb < end; cb += 64) {
    int eL = cb + lane;
    int srcL = (eL < end) ? csr_src[eL] : node;
    float2 xsL = x2[srcL];
    int cnt = end - cb; if (cnt > 64) cnt = 64;
    for (int it = 0; it * 4 < cnt; it++) {
      int idx = it * 4 + grp;
      bool valid = idx < cnt;
      float xsx = __shfl(xsL.x, idx, 64);
      float xsy = __shfl(xsL.y, idx, 64);
      float lg[4];
#pragma unroll
      for (int h = 0; h < 4; h++) {
        f32x2 a2 = (f32x2){0.f, 0.f};
#pragma unroll
        for (int p = 0; p < 2; p++) {
          f32x2 v = A0[h][p] * xsx + A1[h][p] * xsy + R[h][p];
          f32x2 lk;
          lk.x = fmaxf(v.x, 0.2f * v.x);
          lk.y = fmaxf(v.y, 0.2f * v.y);
          a2 += AT[h][p] * lk;
        }
        lg[h] = a2.x + a2.y;
      }
      float t0 = __shfl_xor(lg[0], 1, 64), t1 = __shfl_xor(lg[1], 1, 64);
      float t2 = __shfl_xor(lg[2], 1, 64), t3 = __shfl_xor(lg[3], 1, 64);
      float a0, a1;
      if (sub & 1) { a0 = lg[2] + t2; a1 = lg[3] + t3; }
      else         { a0 = lg[0] + t0; a1 = lg[1] + t1; }
      float u0 = __shfl_xor(a0, 2, 64), u1 = __shfl_xor(a1, 2, 64);
      float b = (sub & 2) ? (a1 + u1) : (a0 + u0);
      b += __shfl_xor(b, 4, 64);
      b += __shfl_xor(b, 8, 64);
      float e = valid ? __expf(b) : 0.f;
      ad += e;
      ax = fmaf(e, xsx, ax);
      ay = fmaf(e, xsy, ay);
    }
  }
  ax += __shfl_xor(ax, 16, 64); ax += __shfl_xor(ax, 32, 64);
  ay += __shfl_xor(ay, 16, 64); ay += __shfl_xor(ay, 32, 64);
  ad += __shfl_xor(ad, 16, 64); ad += __shfl_xor(ad, 32, 64);
  if (lane < 4) {
    int h = ((sub & 1) << 1) | ((sub >> 1) & 1);
    float2 o = {ax / ad, ay / ad};
    *(float2*)(s1 + node * 8 + h * 2) = o;
  }
}

// ---------- node1 via MFMA: s1 -> t=relu(.) bf16 in LDS -> [64x256]@[256x128] ----------
#define TPAD 264  /* bf16 row stride: 528 B, dword stride 132 == 4 mod 32 */
__global__ __launch_bounds__(256) void k_node1(
    const float* __restrict__ s1,
    const float* __restrict__ Wl1, const float* __restrict__ bl1,
    const float* __restrict__ bias1,
    const short* __restrict__ Wb,
    const float* __restrict__ bl2, const float* __restrict__ br2,
    unsigned short* __restrict__ xl2b, unsigned short* __restrict__ xr2b) {
  __shared__ short t_lds[64 * TPAD];
  __shared__ float s_lds[512];
  int tid = threadIdx.x;
  int base = blockIdx.x * 64;

  {
    int g0 = base * 8;
    if (g0 + 512 <= NN * 8) {
      if (tid < 128) {
        float4 v = *(const float4*)(s1 + g0 + tid * 4);
        *(float4*)(s_lds + tid * 4) = v;
      }
    } else {
      for (int i = tid; i < 512; i += 256) {
        int g = g0 + i;
        s_lds[i] = (g < NN * 8) ? s1[g] : 0.f;
      }
    }
  }
  __syncthreads();

  {
    int ch = tid, h = tid >> 6;
    float w0 = Wl1[ch * 2], w1 = Wl1[ch * 2 + 1], bb = bl1[ch] + bias1[ch];
    for (int i = 0; i < 64; i++) {
      float s0 = s_lds[i * 8 + h * 2], sv = s_lds[i * 8 + h * 2 + 1];
      float v = w0 * s0 + w1 * sv + bb;
      t_lds[i * TPAD + ch] = (short)f2bf(v > 0.f ? v : 0.f);
    }
  }
  __syncthreads();

  int lane = tid & 63, w = tid >> 6;
  int row = w * 16 + (lane & 15);
  const short8* wb8 = (const short8*)Wb;
  f32x4 acc[8];
#pragma unroll
  for (int nt = 0; nt < 8; nt++) {
    int ch = nt * 16 + (lane & 15);
    float b = (ch < 64) ? bl2[ch] : br2[ch - 64];
    acc[nt] = (f32x4){b, b, b, b};
  }
#pragma unroll
  for (int ks = 0; ks < 8; ks++) {
    short8 a = *(const short8*)&t_lds[row * TPAD + ks * 32 + (lane >> 4) * 8];
#pragma unroll
    for (int nt = 0; nt < 8; nt++) {
      short8 bfr = wb8[(nt * 8 + ks) * 64 + lane];
      acc[nt] = __builtin_amdgcn_mfma_f32_16x16x32_bf16(a, bfr, acc[nt], 0, 0, 0);
    }
  }
#pragma unroll
  for (int nt = 0; nt < 8; nt++) {
    int ch = nt * 16 + (lane & 15);
#pragma unroll
    for (int r = 0; r < 4; r++) {
      int node = base + w * 16 + (lane >> 4) * 4 + r;
      if (node < NN) {
        unsigned short v = f2bf(acc[nt][r]);
        if (nt < 4) xl2b[node * 64 + ch] = v;
        else        xr2b[node * 64 + (ch - 64)] = v;
      }
    }
  }
}

// ---------- conv2: two-phase (edge-per-lane logits, then chain-free num accum) ----------
__global__ __launch_bounds__(256) void k_conv2(
    const unsigned short* __restrict__ xl2b, const unsigned short* __restrict__ xr2b,
    const int* __restrict__ rowptr, const int* __restrict__ csr_src,
    const float* __restrict__ att2, float* __restrict__ out2) {
  __shared__ float xr_s[4][64];
  __shared__ float at_s[64];
  int tid = threadIdx.x;
  int lane = tid & 63, wv = tid >> 6;
  int node = blockIdx.x * 4 + wv;
  if (tid < 64) at_s[tid] = att2[tid];
  xr_s[wv][lane] = bf2f(xr2b[node * 64 + lane]);
  __syncthreads();
  int sub = lane & 15, grp = lane >> 4;
  float4 num = {0.f, 0.f, 0.f, 0.f};
  float den = 0.f;
  int start = rowptr[node], end = rowptr[node + 1];
  for (int cb = start; cb < end; cb += 64) {
    int cnt = end - cb; if (cnt > 64) cnt = 64;
    int srcL = (lane < cnt) ? csr_src[cb + lane] : node;
    // phase 1: per-lane logit over all 64 channels (no cross-lane ops)
    float v = 0.f;
    const ushort8* row = (const ushort8*)(xl2b + srcL * 64);
#pragma unroll
    for (int c8 = 0; c8 < 8; c8++) {
      ushort8 xlb = row[c8];
      float4 a0 = *(const float4*)(at_s + c8 * 8);
      float4 a1 = *(const float4*)(at_s + c8 * 8 + 4);
      float4 r0 = *(const float4*)(&xr_s[wv][c8 * 8]);
      float4 r1 = *(const float4*)(&xr_s[wv][c8 * 8 + 4]);
      v += a0.x * leaky(bf2f(xlb[0]) + r0.x);
      v += a0.y * leaky(bf2f(xlb[1]) + r0.y);
      v += a0.z * leaky(bf2f(xlb[2]) + r0.z);
      v += a0.w * leaky(bf2f(xlb[3]) + r0.w);
      v += a1.x * leaky(bf2f(xlb[4]) + r1.x);
      v += a1.y * leaky(bf2f(xlb[5]) + r1.y);
      v += a1.z * leaky(bf2f(xlb[6]) + r1.z);
      v += a1.w * leaky(bf2f(xlb[7]) + r1.w);
    }
    float e = (lane < cnt) ? __expf(v) : 0.f;
    den += e;
    // phase 2: num accumulation, 4 edges/iter, no dependent reduce chain
    for (int it = 0; it * 4 < cnt; it++) {
      int idx = it * 4 + grp;
      int src = __shfl(srcL, idx, 64);
      float ee = __shfl(e, idx, 64);
      ushort4 xlb = *(const ushort4*)(xl2b + src * 64 + sub * 4);
      num.x = fmaf(ee, bf2f(xlb.x), num.x);
      num.y = fmaf(ee, bf2f(xlb.y), num.y);
      num.z = fmaf(ee, bf2f(xlb.z), num.z);
      num.w = fmaf(ee, bf2f(xlb.w), num.w);
    }
  }
#pragma unroll
  for (int off = 16; off <= 32; off <<= 1) {
    num.x += __shfl_xor(num.x, off, 64);
    num.y += __shfl_xor(num.y, off, 64);
    num.z += __shfl_xor(num.z, off, 64);
    num.w += __shfl_xor(num.w, off, 64);
  }
#pragma unroll
  for (int off = 1; off <= 32; off <<= 1) den += __shfl_xor(den, off, 64);
  if (grp == 0) {
    float4 o = {num.x / den, num.y / den, num.z / den, num.w / den};
    *(float4*)(out2 + node * 64 + sub * 4) = o;
  }
}

// ---------- pooling: wave per 32 contiguous nodes (batch sorted) ----------
__global__ void k_pool(const float* __restrict__ out2, const int* __restrict__ batch,
                       float* __restrict__ pool, float* __restrict__ counts) {
  int lane = threadIdx.x & 63;
  int wid = blockIdx.x * 4 + (threadIdx.x >> 6);
  int start = wid * 32;
  if (start >= NN) return;
  int end = start + 32; if (end > NN) end = NN;
  int cur = batch[start];
  float acc = 0.f; int cnt = 0;
  for (int node = start; node < end; node++) {
    int b = batch[node];
    if (b != cur) {
      atomicAdd(&pool[cur * 64 + lane], acc);
      if (lane == 0) atomicAdd(&counts[cur], (float)cnt);
      acc = 0.f; cnt = 0; cur = b;
    }
    acc += out2[node * 64 + lane];
    cnt++;
  }
  atomicAdd(&pool[cur * 64 + lane], acc);
  if (lane == 0) atomicAdd(&counts[cur], (float)cnt);
}

// ---------- final: mean + MLP, one block per graph, LDS activations ----------
__global__ void k_final(const float* __restrict__ pool, const float* __restrict__ counts,
                        const float* __restrict__ bias2, const float* __restrict__ bk,
                        const float* __restrict__ wc1, const float* __restrict__ bc1,
                        const float* __restrict__ wc2, const float* __restrict__ bc2,
                        const float* __restrict__ wc3, const float* __restrict__ bc3,
                        float* __restrict__ out) {
  __shared__ float sge[65], sc1[32], sc2[16];
  int g = blockIdx.x, t = threadIdx.x;
  if (t < 64) {
    float cnt = counts[g]; cnt = cnt > 1.f ? cnt : 1.f;
    sge[t] = pool[g * 64 + t] / cnt + bias2[t];
  }
  if (t == 0) sge[64] = bk[g];
  __syncthreads();
  if (t < 32) {
    float a = bc1[t];
    for (int k = 0; k < 65; k++) a += wc1[t * 65 + k] * sge[k];
    sc1[t] = a > 0.f ? a : 0.f;
  }
  __syncthreads();
  if (t < 16) {
    float a = bc2[t];
    for (int k = 0; k < 32; k++) a += wc2[t * 32 + k] * sc1[k];
    sc2[t] = a > 0.f ? a : 0.f;
  }
  __syncthreads();
  if (t == 0) {
    float a = bc3[0];
    for (int k = 0; k < 16; k++) a += wc3[k] * sc2[k];
    out[g] = bk[g] + a;
  }
}

extern "C" void kernel_launch(void* const* d_in, const int* in_sizes, int n_in,
                              void* d_out, int out_size, void* d_ws, size_t ws_size,
                              hipStream_t stream) {
  (void)in_sizes; (void)n_in; (void)out_size; (void)ws_size;
  const float* x     = (const float*)d_in[0];
  const int*   ei    = (const int*)d_in[1];
  const int*   batch = (const int*)d_in[2];
  const float* bk    = (const float*)d_in[3];
  const float* Wl1   = (const float*)d_in[4];
  const float* bl1   = (const float*)d_in[5];
  const float* Wr1   = (const float*)d_in[6];
  const float* br1   = (const float*)d_in[7];
  const float* att1  = (const float*)d_in[8];
  const float* bias1 = (const float*)d_in[9];
  const float* Wl2   = (const float*)d_in[10];
  const float* bl2   = (const float*)d_in[11];
  const float* Wr2   = (const float*)d_in[12];
  const float* br2   = (const float*)d_in[13];
  const float* att2  = (const float*)d_in[14];
  const float* bias2 = (const float*)d_in[15];
  const float* wc1   = (const float*)d_in[16];
  const float* bc1   = (const float*)d_in[17];
  const float* wc2   = (const float*)d_in[18];
  const float* bc2   = (const float*)d_in[19];
  const float* wc3   = (const float*)d_in[20];
  const float* bc3   = (const float*)d_in[21];
  float* out = (float*)d_out;

  float* ws = (float*)d_ws;
  // ---- zeroed region: [0, 4160) ----
  float* pool    = ws + 0;                // [G*64]   4096
  float* cnts    = ws + 4096;             // [G]      64
  // ---- write-before-read region ----
  int*   rowptr  = (int*)(ws + 4160);     // [N+1]    50004
  int*   bktbase = (int*)(ws + 54164);    // [NBKT+1] 260
  int*   bcur    = (int*)(ws + 54424);    // [NBKT]   256 (+pad)
  int*   csr_src = (int*)(ws + 54680);    // [NT]     850000
  float* s1      = ws + 904680;           // [N*4*2]  400000
  unsigned short* xl2b = (unsigned short*)(ws + 1304680); // [N*64] bf16
  unsigned short* xr2b = (unsigned short*)(ws + 2904680); // [N*64] bf16
  float* out2    = ws + 4504680;          // [N*64]   3200000
  short* Wb      = (short*)(ws + 7704680); // [128*256] bf16 = 8192 f
  int2*  staging = (int2*)(ws + 7712872); // [NBKT*CAP] int2 = 2007040 f

  hipMemsetAsync(ws, 0, 4160 * sizeof(float), stream);

  k_prep<<<129, 256, 0, stream>>>(Wl2, Wr2, Wb, bcur);
  k_passA<<<NA, 256, 0, stream>>>(ei, bcur, staging);
  k_bktscan2<<<1, 256, 0, stream>>>(bcur, bktbase);
  k_passB<<<NBKT, 256, 0, stream>>>(bktbase, bcur, staging, rowptr, csr_src);

  k_conv1<<<NN / 4, 256, 0, stream>>>(x, rowptr, csr_src, Wl1, bl1, Wr1, br1, att1, s1);
  k_node1<<<(NN + 63) / 64, 256, 0, stream>>>(s1, Wl1, bl1, bias1, Wb, bl2, br2, xl2b, xr2b);
  k_conv2<<<NN / 4, 256, 0, stream>>>(xl2b, xr2b, rowptr, csr_src, att2, out2);

  k_pool<<<(((NN + 31) / 32) + 3) / 4, 256, 0, stream>>>(out2, batch, pool, cnts);
  k_final<<<NG, 64, 0, stream>>>(pool, cnts, bias2, bk, wc1, bc1, wc2, bc2, wc3, bc3, out);
}

// Round 19
// 191.247 us; speedup vs baseline: 1.3030x; 1.3030x over previous
//
#include <hip/hip_runtime.h>

#define NN 50000
#define NE 800000
#define NT (NE + NN)   /* 850000 edges incl self-loops */
#define NG 64
#define NBKT ((NN + 255) / 256)  /* 196 dst buckets of 256 nodes */
#define CAP 5120               /* staging capacity per bucket (mean 4352, +11.7 sigma) */
#define CHA 4096               /* pass-A edges per block */
#define NA ((NT + CHA - 1) / CHA) /* 208 pass-A blocks */

typedef __attribute__((ext_vector_type(8))) short short8;
typedef __attribute__((ext_vector_type(4))) float f32x4;
typedef __attribute__((ext_vector_type(2))) float f32x2;

__device__ __forceinline__ float leaky(float v) { return fmaxf(v, 0.2f * v); }

__device__ __forceinline__ unsigned short f2bf(float f) {
  unsigned u = __float_as_uint(f);
  unsigned r = (u + 0x7fffu + ((u >> 16) & 1u)) >> 16;
  return (unsigned short)r;
}
__device__ __forceinline__ float bf2f(unsigned short s) {
  return __uint_as_float(((unsigned)s) << 16);
}

// ---------- prep: Wl2||Wr2 -> bf16 (128 blocks) + bcur init (1 block) ----------
__global__ void k_prep(const float* __restrict__ Wl2, const float* __restrict__ Wr2,
                       short* __restrict__ Wb, int* __restrict__ bcur) {
  int b = blockIdx.x;
  if (b < 128) {
    int idx = b * 256 + threadIdx.x;  // 128*256 elems
    int n = idx >> 8, k = idx & 255;
    float v = (n < 64) ? Wl2[n * 256 + k] : Wr2[(n - 64) * 256 + k];
    int nt = n >> 4, ks = k >> 5;
    int l = (n & 15) + (((k >> 3) & 3) << 4);
    int j = k & 7;
    Wb[(((nt * 8 + ks) * 64 + l) << 3) + j] = (short)f2bf(v);
  } else {
    int t = threadIdx.x;
    if (t < NBKT) bcur[t] = t * CAP;
  }
}

// ---------- pass A: bucket the edges into fixed-capacity staging ----------
__global__ __launch_bounds__(256) void k_passA(const int* __restrict__ ei,
                                               int* __restrict__ bcur,
                                               int2* __restrict__ staging) {
  __shared__ int hist[NBKT];
  __shared__ int cur[NBKT];
  int t = threadIdx.x;
  int e0 = blockIdx.x * CHA;
  for (int i = t; i < NBKT; i += 256) hist[i] = 0;
  __syncthreads();
  for (int i = t; i < CHA; i += 256) {
    int e = e0 + i;
    if (e < NT) {
      int dst = (e < NE) ? ei[NE + e] : e - NE;
      atomicAdd(&hist[dst >> 8], 1);
    }
  }
  __syncthreads();
  for (int i = t; i < NBKT; i += 256) {
    int h = hist[i];
    cur[i] = h ? atomicAdd(&bcur[i], h) : 0;
  }
  __syncthreads();
  for (int i = t; i < CHA; i += 256) {
    int e = e0 + i;
    if (e < NT) {
      int src, dst;
      if (e < NE) { src = ei[e]; dst = ei[NE + e]; } else { src = dst = e - NE; }
      int pos = atomicAdd(&cur[dst >> 8], 1);
      staging[pos] = make_int2(src, dst);
    }
  }
}

// ---------- bucket scan: counts (from bcur) -> CSR bases (one block) ----------
__global__ __launch_bounds__(256) void k_bktscan2(const int* __restrict__ bcur,
                                                  int* __restrict__ bktbase) {
  __shared__ int wsum[4];
  int t = threadIdx.x;
  int lane = t & 63, w = t >> 6;
  int v = (t < NBKT) ? (bcur[t] - t * CAP) : 0;
  int incl = v;
#pragma unroll
  for (int off = 1; off < 64; off <<= 1) {
    int u = __shfl_up(incl, off, 64);
    if (lane >= off) incl += u;
  }
  if (lane == 63) wsum[w] = incl;
  __syncthreads();
  int woff = 0;
  for (int i = 0; i < w; i++) woff += wsum[i];
  int excl = woff + incl - v;
  if (t < NBKT) bktbase[t] = excl;
  if (t == 0) bktbase[NBKT] = NT;
}

// ---------- pass B: node hist + scan -> rowptr; scatter csr_src (L2-local) ----------
__global__ __launch_bounds__(256) void k_passB(const int* __restrict__ bktbase,
                                               const int* __restrict__ bcur,
                                               const int2* __restrict__ staging,
                                               int* __restrict__ rowptr,
                                               int* __restrict__ csr_src) {
  __shared__ int cnt[256];
  __shared__ int wsum[4];
  __shared__ int cur[256];
  int b = blockIdx.x, t = threadIdx.x;
  int nb0 = b * 256;
  int s0 = b * CAP;                 // staging base
  int s1v = bcur[b];                // staging end
  int r0 = bktbase[b];              // CSR base
  cnt[t] = 0;
  __syncthreads();
  for (int i = s0 + t; i < s1v; i += 256)
    atomicAdd(&cnt[staging[i].y - nb0], 1);
  __syncthreads();
  int v = cnt[t];
  int lane = t & 63, w = t >> 6;
  int incl = v;
#pragma unroll
  for (int off = 1; off < 64; off <<= 1) {
    int u = __shfl_up(incl, off, 64);
    if (lane >= off) incl += u;
  }
  if (lane == 63) wsum[w] = incl;
  __syncthreads();
  int woff = 0;
  for (int i = 0; i < w; i++) woff += wsum[i];
  int base = r0 + woff + incl - v;   // exclusive within bucket
  if (nb0 + t < NN) rowptr[nb0 + t] = base;
  if (b == NBKT - 1 && t == 0) rowptr[NN] = NT;
  cur[t] = base;
  __syncthreads();
  for (int i = s0 + t; i < s1v; i += 256) {
    int2 e = staging[i];
    int pos = atomicAdd(&cur[e.y - nb0], 1);
    csr_src[pos] = e.x;
  }
}

// ---------- conv1: EXACT R12-measured kernel (76.0us) ----------
__global__ __launch_bounds__(256) void k_conv1(
    const float* __restrict__ x, const int* __restrict__ rowptr,
    const int* __restrict__ csr_src,
    const float* __restrict__ Wl1, const float* __restrict__ bl1,
    const float* __restrict__ Wr1, const float* __restrict__ br1,
    const float* __restrict__ att1, float* __restrict__ s1) {
  int lane = threadIdx.x & 63;
  int node = blockIdx.x * 4 + (threadIdx.x >> 6);
  if (node >= NN) return;
  int sub = lane & 15, grp = lane >> 4;
  const float2* x2 = (const float2*)x;
  float2 xd = x2[node];
  f32x2 A0[4][2], A1[4][2], R[4][2], AT[4][2];
#pragma unroll
  for (int h = 0; h < 4; h++)
#pragma unroll
    for (int p = 0; p < 2; p++) {
      int c0 = h * 64 + sub * 4 + 2 * p;
      A0[h][p] = (f32x2){Wl1[c0 * 2], Wl1[(c0 + 1) * 2]};
      A1[h][p] = (f32x2){Wl1[c0 * 2 + 1], Wl1[(c0 + 1) * 2 + 1]};
      R[h][p]  = (f32x2){Wr1[c0 * 2] * xd.x + Wr1[c0 * 2 + 1] * xd.y + bl1[c0] + br1[c0],
                         Wr1[(c0 + 1) * 2] * xd.x + Wr1[(c0 + 1) * 2 + 1] * xd.y + bl1[c0 + 1] + br1[c0 + 1]};
      AT[h][p] = (f32x2){att1[c0], att1[c0 + 1]};
    }
  float ax = 0.f, ay = 0.f, ad = 0.f;
  int start = rowptr[node], end = rowptr[node + 1];
  for (int cb = start; cb < end; cb += 64) {
    int eL = cb + lane;
    int srcL = (eL < end) ? csr_src[eL] : node;
    float2 xsL = x2[srcL];
    int cnt = end - cb; if (cnt > 64) cnt = 64;
    for (int it = 0; it * 4 < cnt; it++) {
      int idx = it * 4 + grp;
      bool valid = idx < cnt;
      float xsx = __shfl(xsL.x, idx, 64);
      float xsy = __shfl(xsL.y, idx, 64);
      float lg[4];
#pragma unroll
      for (int h = 0; h < 4; h++) {
        f32x2 a2 = (f32x2){0.f, 0.f};
#pragma unroll
        for (int p = 0; p < 2; p++) {
          f32x2 v = A0[h][p] * xsx + A1[h][p] * xsy + R[h][p];
          f32x2 lk;
          lk.x = fmaxf(v.x, 0.2f * v.x);
          lk.y = fmaxf(v.y, 0.2f * v.y);
          a2 += AT[h][p] * lk;
        }
        lg[h] = a2.x + a2.y;
      }
      float t0 = __shfl_xor(lg[0], 1, 64), t1 = __shfl_xor(lg[1], 1, 64);
      float t2 = __shfl_xor(lg[2], 1, 64), t3 = __shfl_xor(lg[3], 1, 64);
      float a0, a1;
      if (sub & 1) { a0 = lg[2] + t2; a1 = lg[3] + t3; }
      else         { a0 = lg[0] + t0; a1 = lg[1] + t1; }
      float u0 = __shfl_xor(a0, 2, 64), u1 = __shfl_xor(a1, 2, 64);
      float b = (sub & 2) ? (a1 + u1) : (a0 + u0);
      b += __shfl_xor(b, 4, 64);
      b += __shfl_xor(b, 8, 64);
      float e = valid ? __expf(b) : 0.f;
      ad += e;
      ax = fmaf(e, xsx, ax);
      ay = fmaf(e, xsy, ay);
    }
  }
  ax += __shfl_xor(ax, 16, 64); ax += __shfl_xor(ax, 32, 64);
  ay += __shfl_xor(ay, 16, 64); ay += __shfl_xor(ay, 32, 64);
  ad += __shfl_xor(ad, 16, 64); ad += __shfl_xor(ad, 32, 64);
  if (lane < 4) {
    int h = ((sub & 1) << 1) | ((sub >> 1) & 1);
    float2 o = {ax / ad, ay / ad};
    *(float2*)(s1 + node * 8 + h * 2) = o;
  }
}

// ---------- node1 via MFMA: s1 -> t=relu(.) bf16 in LDS -> [64x256]@[256x128] ----------
#define TPAD 264  /* bf16 row stride: 528 B, dword stride 132 == 4 mod 32 */
__global__ __launch_bounds__(256) void k_node1(
    const float* __restrict__ s1,
    const float* __restrict__ Wl1, const float* __restrict__ bl1,
    const float* __restrict__ bias1,
    const short* __restrict__ Wb,
    const float* __restrict__ bl2, const float* __restrict__ br2,
    unsigned short* __restrict__ xl2b, unsigned short* __restrict__ xr2b) {
  __shared__ short t_lds[64 * TPAD];
  __shared__ float s_lds[512];
  int tid = threadIdx.x;
  int base = blockIdx.x * 64;

  {
    int g0 = base * 8;
    if (g0 + 512 <= NN * 8) {
      if (tid < 128) {
        float4 v = *(const float4*)(s1 + g0 + tid * 4);
        *(float4*)(s_lds + tid * 4) = v;
      }
    } else {
      for (int i = tid; i < 512; i += 256) {
        int g = g0 + i;
        s_lds[i] = (g < NN * 8) ? s1[g] : 0.f;
      }
    }
  }
  __syncthreads();

  {
    int ch = tid, h = tid >> 6;
    float w0 = Wl1[ch * 2], w1 = Wl1[ch * 2 + 1], bb = bl1[ch] + bias1[ch];
    for (int i = 0; i < 64; i++) {
      float s0 = s_lds[i * 8 + h * 2], sv = s_lds[i * 8 + h * 2 + 1];
      float v = w0 * s0 + w1 * sv + bb;
      t_lds[i * TPAD + ch] = (short)f2bf(v > 0.f ? v : 0.f);
    }
  }
  __syncthreads();

  int lane = tid & 63, w = tid >> 6;
  int row = w * 16 + (lane & 15);
  const short8* wb8 = (const short8*)Wb;
  f32x4 acc[8];
#pragma unroll
  for (int nt = 0; nt < 8; nt++) {
    int ch = nt * 16 + (lane & 15);
    float b = (ch < 64) ? bl2[ch] : br2[ch - 64];
    acc[nt] = (f32x4){b, b, b, b};
  }
#pragma unroll
  for (int ks = 0; ks < 8; ks++) {
    short8 a = *(const short8*)&t_lds[row * TPAD + ks * 32 + (lane >> 4) * 8];
#pragma unroll
    for (int nt = 0; nt < 8; nt++) {
      short8 bfr = wb8[(nt * 8 + ks) * 64 + lane];
      acc[nt] = __builtin_amdgcn_mfma_f32_16x16x32_bf16(a, bfr, acc[nt], 0, 0, 0);
    }
  }
#pragma unroll
  for (int nt = 0; nt < 8; nt++) {
    int ch = nt * 16 + (lane & 15);
#pragma unroll
    for (int r = 0; r < 4; r++) {
      int node = base + w * 16 + (lane >> 4) * 4 + r;
      if (node < NN) {
        unsigned short v = f2bf(acc[nt][r]);
        if (nt < 4) xl2b[node * 64 + ch] = v;
        else        xr2b[node * 64 + (ch - 64)] = v;
      }
    }
  }
}

// ---------- conv2: R10-measured structure (4 edges/iter, bf16 gathers) ----------
__global__ __launch_bounds__(256) void k_conv2(
    const unsigned short* __restrict__ xl2b, const unsigned short* __restrict__ xr2b,
    const int* __restrict__ rowptr, const int* __restrict__ csr_src,
    const float* __restrict__ att2, float* __restrict__ out2) {
  int lane = threadIdx.x & 63;
  int node = blockIdx.x * 4 + (threadIdx.x >> 6);
  if (node >= NN) return;
  int sub = lane & 15, grp = lane >> 4;
  float4 at = *(const float4*)(att2 + sub * 4);
  ushort4 xrb = *(const ushort4*)(xr2b + node * 64 + sub * 4);
  float4 xr = {bf2f(xrb.x), bf2f(xrb.y), bf2f(xrb.z), bf2f(xrb.w)};
  float4 num = {0.f, 0.f, 0.f, 0.f};
  float den = 0.f;
  int start = rowptr[node], end = rowptr[node + 1];
  for (int cb = start; cb < end; cb += 64) {
    int eL = cb + lane;
    int srcL = (eL < end) ? csr_src[eL] : node;
    int cnt = end - cb; if (cnt > 64) cnt = 64;
    for (int it = 0; it * 4 < cnt; it++) {
      int idx = it * 4 + grp;
      bool valid = idx < cnt;
      int src = __shfl(srcL, idx, 64);
      ushort4 xlb = *(const ushort4*)(xl2b + src * 64 + sub * 4);
      float4 xl = {bf2f(xlb.x), bf2f(xlb.y), bf2f(xlb.z), bf2f(xlb.w)};
      float v = at.x * leaky(xl.x + xr.x) + at.y * leaky(xl.y + xr.y)
              + at.z * leaky(xl.z + xr.z) + at.w * leaky(xl.w + xr.w);
      v += __shfl_xor(v, 1, 64);
      v += __shfl_xor(v, 2, 64);
      v += __shfl_xor(v, 4, 64);
      v += __shfl_xor(v, 8, 64);
      float e = valid ? __expf(v) : 0.f;
      num.x = fmaf(e, xl.x, num.x); num.y = fmaf(e, xl.y, num.y);
      num.z = fmaf(e, xl.z, num.z); num.w = fmaf(e, xl.w, num.w);
      den += e;
    }
  }
#pragma unroll
  for (int off = 16; off <= 32; off <<= 1) {
    num.x += __shfl_xor(num.x, off, 64);
    num.y += __shfl_xor(num.y, off, 64);
    num.z += __shfl_xor(num.z, off, 64);
    num.w += __shfl_xor(num.w, off, 64);
    den   += __shfl_xor(den, off, 64);
  }
  if (grp == 0) {
    float4 o = {num.x / den, num.y / den, num.z / den, num.w / den};
    *(float4*)(out2 + node * 64 + sub * 4) = o;
  }
}

// ---------- pooling: wave per 32 contiguous nodes (batch sorted) ----------
__global__ void k_pool(const float* __restrict__ out2, const int* __restrict__ batch,
                       float* __restrict__ pool, float* __restrict__ counts) {
  int lane = threadIdx.x & 63;
  int wid = blockIdx.x * 4 + (threadIdx.x >> 6);
  int start = wid * 32;
  if (start >= NN) return;
  int end = start + 32; if (end > NN) end = NN;
  int cur = batch[start];
  float acc = 0.f; int cnt = 0;
  for (int node = start; node < end; node++) {
    int b = batch[node];
    if (b != cur) {
      atomicAdd(&pool[cur * 64 + lane], acc);
      if (lane == 0) atomicAdd(&counts[cur], (float)cnt);
      acc = 0.f; cnt = 0; cur = b;
    }
    acc += out2[node * 64 + lane];
    cnt++;
  }
  atomicAdd(&pool[cur * 64 + lane], acc);
  if (lane == 0) atomicAdd(&counts[cur], (float)cnt);
}

// ---------- final: mean + MLP, one block per graph, LDS activations ----------
__global__ void k_final(const float* __restrict__ pool, const float* __restrict__ counts,
                        const float* __restrict__ bias2, const float* __restrict__ bk,
                        const float* __restrict__ wc1, const float* __restrict__ bc1,
                        const float* __restrict__ wc2, const float* __restrict__ bc2,
                        const float* __restrict__ wc3, const float* __restrict__ bc3,
                        float* __restrict__ out) {
  __shared__ float sge[65], sc1[32], sc2[16];
  int g = blockIdx.x, t = threadIdx.x;
  if (t < 64) {
    float cnt = counts[g]; cnt = cnt > 1.f ? cnt : 1.f;
    sge[t] = pool[g * 64 + t] / cnt + bias2[t];
  }
  if (t == 0) sge[64] = bk[g];
  __syncthreads();
  if (t < 32) {
    float a = bc1[t];
    for (int k = 0; k < 65; k++) a += wc1[t * 65 + k] * sge[k];
    sc1[t] = a > 0.f ? a : 0.f;
  }
  __syncthreads();
  if (t < 16) {
    float a = bc2[t];
    for (int k = 0; k < 32; k++) a += wc2[t * 32 + k] * sc1[k];
    sc2[t] = a > 0.f ? a : 0.f;
  }
  __syncthreads();
  if (t == 0) {
    float a = bc3[0];
    for (int k = 0; k < 16; k++) a += wc3[k] * sc2[k];
    out[g] = bk[g] + a;
  }
}

extern "C" void kernel_launch(void* const* d_in, const int* in_sizes, int n_in,
                              void* d_out, int out_size, void* d_ws, size_t ws_size,
                              hipStream_t stream) {
  (void)in_sizes; (void)n_in; (void)out_size; (void)ws_size;
  const float* x     = (const float*)d_in[0];
  const int*   ei    = (const int*)d_in[1];
  const int*   batch = (const int*)d_in[2];
  const float* bk    = (const float*)d_in[3];
  const float* Wl1   = (const float*)d_in[4];
  const float* bl1   = (const float*)d_in[5];
  const float* Wr1   = (const float*)d_in[6];
  const float* br1   = (const float*)d_in[7];
  const float* att1  = (const float*)d_in[8];
  const float* bias1 = (const float*)d_in[9];
  const float* Wl2   = (const float*)d_in[10];
  const float* bl2   = (const float*)d_in[11];
  const float* Wr2   = (const float*)d_in[12];
  const float* br2   = (const float*)d_in[13];
  const float* att2  = (const float*)d_in[14];
  const float* bias2 = (const float*)d_in[15];
  const float* wc1   = (const float*)d_in[16];
  const float* bc1   = (const float*)d_in[17];
  const float* wc2   = (const float*)d_in[18];
  const float* bc2   = (const float*)d_in[19];
  const float* wc3   = (const float*)d_in[20];
  const float* bc3   = (const float*)d_in[21];
  float* out = (float*)d_out;

  float* ws = (float*)d_ws;
  // ---- zeroed region: [0, 4160) ----
  float* pool    = ws + 0;                // [G*64]   4096
  float* cnts    = ws + 4096;             // [G]      64
  // ---- write-before-read region ----
  int*   rowptr  = (int*)(ws + 4160);     // [N+1]    50004
  int*   bktbase = (int*)(ws + 54164);    // [NBKT+1] 260
  int*   bcur    = (int*)(ws + 54424);    // [NBKT]   256 (+pad)
  int*   csr_src = (int*)(ws + 54680);    // [NT]     850000
  float* s1      = ws + 904680;           // [N*4*2]  400000
  unsigned short* xl2b = (unsigned short*)(ws + 1304680); // [N*64] bf16
  unsigned short* xr2b = (unsigned short*)(ws + 2904680); // [N*64] bf16
  float* out2    = ws + 4504680;          // [N*64]   3200000
  short* Wb      = (short*)(ws + 7704680); // [128*256] bf16 = 8192 f
  int2*  staging = (int2*)(ws + 7712872); // [NBKT*CAP] int2 = 2007040 f

  hipMemsetAsync(ws, 0, 4160 * sizeof(float), stream);

  k_prep<<<129, 256, 0, stream>>>(Wl2, Wr2, Wb, bcur);
  k_passA<<<NA, 256, 0, stream>>>(ei, bcur, staging);
  k_bktscan2<<<1, 256, 0, stream>>>(bcur, bktbase);
  k_passB<<<NBKT, 256, 0, stream>>>(bktbase, bcur, staging, rowptr, csr_src);

  k_conv1<<<NN / 4, 256, 0, stream>>>(x, rowptr, csr_src, Wl1, bl1, Wr1, br1, att1, s1);
  k_node1<<<(NN + 63) / 64, 256, 0, stream>>>(s1, Wl1, bl1, bias1, Wb, bl2, br2, xl2b, xr2b);
  k_conv2<<<NN / 4, 256, 0, stream>>>(xl2b, xr2b, rowptr, csr_src, att2, out2);

  k_pool<<<(((NN + 31) / 32) + 3) / 4, 256, 0, stream>>>(out2, batch, pool, cnts);
  k_final<<<NG, 64, 0, stream>>>(pool, cnts, bias2, bk, wc1, bc1, wc2, bc2, wc3, bc3, out);
}